// Round 1
// baseline (845.731 us; speedup 1.0000x reference)
//
#include <hip/hip_runtime.h>
#include <hip/hip_bf16.h>

#define N_NODES 50000
#define N_EDGES 400000
#define IN_DIM 128
#define HID 64
#define HEADS 4
#define L1_OUT (HEADS * HID)   // 256
#define OUT_DIM 64
#define NEG_SLOPE 0.2f

// ---- monotonic float<->uint encoding for atomicMax-based segment max ----
__device__ __forceinline__ unsigned fenc(float x) {
    unsigned b = __float_as_uint(x);
    return b ^ (unsigned)(((int)b >> 31) | 0x80000000);
}
__device__ __forceinline__ float fdec(unsigned k) {
    unsigned m = (unsigned)(((int)(~k) >> 31)) | 0x80000000u;
    return __uint_as_float(k ^ m);
}
#define FENC_NEG_INF 0x007FFFFFu   // fenc(-inf)

// ------------------- init -------------------
__global__ void init_emax_kernel(unsigned* emax1, unsigned* emax2) {
    int i = blockIdx.x * blockDim.x + threadIdx.x;
    if (i < N_NODES * HEADS) emax1[i] = FENC_NEG_INF;
    if (i < N_NODES) emax2[i] = FENC_NEG_INF;
}

// ------------------- layer 1 GEMM + el/er -------------------
// one node per block, 256 threads; c = h*64+d
__global__ void gemm1_kernel(const float* __restrict__ X, const float* __restrict__ W1,
                             const float* __restrict__ al, const float* __restrict__ ar,
                             float* __restrict__ feat1, float* __restrict__ el1,
                             float* __restrict__ er1) {
    __shared__ float xrow[IN_DIM];
    int n = blockIdx.x;
    int c = threadIdx.x;
    if (c < IN_DIM) xrow[c] = X[n * IN_DIM + c];
    __syncthreads();
    float acc = 0.f;
#pragma unroll 8
    for (int k = 0; k < IN_DIM; ++k) acc += xrow[k] * W1[k * L1_OUT + c];
    feat1[n * L1_OUT + c] = acc;
    float l = acc * al[c];
    float r = acc * ar[c];
#pragma unroll
    for (int off = 32; off > 0; off >>= 1) {
        l += __shfl_down(l, off, 64);
        r += __shfl_down(r, off, 64);
    }
    if ((c & 63) == 0) {
        int h = c >> 6;
        el1[n * HEADS + h] = l;
        er1[n * HEADS + h] = r;
    }
}

// ------------------- layer 1 edge passes -------------------
__global__ void edge1_logits_kernel(const int* __restrict__ src, const int* __restrict__ dst,
                                    const float* __restrict__ el1, const float* __restrict__ er1,
                                    float* __restrict__ e1, unsigned* __restrict__ emax1) {
    int idx = blockIdx.x * blockDim.x + threadIdx.x;
    if (idx >= N_EDGES * HEADS) return;
    int e = idx >> 2, h = idx & 3;
    float s = el1[src[e] * HEADS + h] + er1[dst[e] * HEADS + h];
    s = s > 0.f ? s : NEG_SLOPE * s;
    e1[idx] = s;
    atomicMax(&emax1[dst[e] * HEADS + h], fenc(s));
}

__global__ void edge1_exp_kernel(const int* __restrict__ dst, float* __restrict__ e1,
                                 const unsigned* __restrict__ emax1,
                                 float* __restrict__ denom1) {
    int idx = blockIdx.x * blockDim.x + threadIdx.x;
    if (idx >= N_EDGES * HEADS) return;
    int e = idx >> 2, h = idx & 3;
    float m = fdec(emax1[dst[e] * HEADS + h]);
    float ex = expf(e1[idx] - m);
    e1[idx] = ex;
    atomicAdd(&denom1[dst[e] * HEADS + h], ex);
}

// one edge per block, 256 threads (c = h*64+d)
__global__ void edge1_scatter_kernel(const int* __restrict__ src, const int* __restrict__ dst,
                                     const float* __restrict__ e1, const float* __restrict__ denom1,
                                     const float* __restrict__ feat1, float* __restrict__ rst1) {
    int e = blockIdx.x;
    int c = threadIdx.x;
    int h = c >> 6;
    int s = src[e], d = dst[e];
    float alpha = e1[e * HEADS + h] / denom1[d * HEADS + h];
    atomicAdd(&rst1[d * L1_OUT + c], alpha * feat1[s * L1_OUT + c]);
}

// ------------------- layer 2 GEMM + el/er -------------------
// one node per block, 64 threads (one wave)
__global__ void gemm2_kernel(const float* __restrict__ rst1, const float* __restrict__ b1,
                             const float* __restrict__ W2, const float* __restrict__ al2,
                             const float* __restrict__ ar2, float* __restrict__ feat2,
                             float* __restrict__ el2, float* __restrict__ er2) {
    __shared__ float row[L1_OUT];
    int n = blockIdx.x;
    int t = threadIdx.x;
    for (int i = t; i < L1_OUT; i += 64) row[i] = rst1[n * L1_OUT + i] + b1[i];
    __syncthreads();
    float acc = 0.f;
#pragma unroll 8
    for (int k = 0; k < L1_OUT; ++k) acc += row[k] * W2[k * OUT_DIM + t];
    feat2[n * OUT_DIM + t] = acc;
    float l = acc * al2[t];
    float r = acc * ar2[t];
#pragma unroll
    for (int off = 32; off > 0; off >>= 1) {
        l += __shfl_down(l, off, 64);
        r += __shfl_down(r, off, 64);
    }
    if (t == 0) {
        el2[n] = l;
        er2[n] = r;
    }
}

// ------------------- layer 2 edge passes -------------------
__global__ void edge2_logits_kernel(const int* __restrict__ src, const int* __restrict__ dst,
                                    const float* __restrict__ el2, const float* __restrict__ er2,
                                    float* __restrict__ e2, unsigned* __restrict__ emax2) {
    int e = blockIdx.x * blockDim.x + threadIdx.x;
    if (e >= N_EDGES) return;
    float s = el2[src[e]] + er2[dst[e]];
    s = s > 0.f ? s : NEG_SLOPE * s;
    e2[e] = s;
    atomicMax(&emax2[dst[e]], fenc(s));
}

__global__ void edge2_exp_kernel(const int* __restrict__ dst, float* __restrict__ e2,
                                 const unsigned* __restrict__ emax2,
                                 float* __restrict__ denom2) {
    int e = blockIdx.x * blockDim.x + threadIdx.x;
    if (e >= N_EDGES) return;
    float m = fdec(emax2[dst[e]]);
    float ex = expf(e2[e] - m);
    e2[e] = ex;
    atomicAdd(&denom2[dst[e]], ex);
}

// one edge per block, 64 threads
__global__ void edge2_scatter_kernel(const int* __restrict__ src, const int* __restrict__ dst,
                                     const float* __restrict__ e2, const float* __restrict__ denom2,
                                     const float* __restrict__ feat2, float* __restrict__ out) {
    int e = blockIdx.x;
    int c = threadIdx.x;
    int s = src[e], d = dst[e];
    float alpha = e2[e] / denom2[d];
    atomicAdd(&out[d * OUT_DIM + c], alpha * feat2[s * OUT_DIM + c]);
}

__global__ void bias2_kernel(float* __restrict__ out, const float* __restrict__ b2) {
    int i = blockIdx.x * blockDim.x + threadIdx.x;
    if (i >= N_NODES * OUT_DIM) return;
    out[i] += b2[i & (OUT_DIM - 1)];
}

extern "C" void kernel_launch(void* const* d_in, const int* in_sizes, int n_in,
                              void* d_out, int out_size, void* d_ws, size_t ws_size,
                              hipStream_t stream) {
    const float* features = (const float*)d_in[0];
    const int* src = (const int*)d_in[1];
    const int* dst = (const int*)d_in[2];
    const float* W1 = (const float*)d_in[3];
    const float* al1 = (const float*)d_in[4];
    const float* ar1 = (const float*)d_in[5];
    const float* b1 = (const float*)d_in[6];
    const float* W2 = (const float*)d_in[7];
    const float* al2 = (const float*)d_in[8];
    const float* ar2 = (const float*)d_in[9];
    const float* b2 = (const float*)d_in[10];
    float* out = (float*)d_out;

    // workspace layout (floats)
    float* ws = (float*)d_ws;
    float* feat1 = ws;                          // N*256
    float* rst1 = feat1 + N_NODES * L1_OUT;     // N*256
    float* feat2 = rst1 + N_NODES * L1_OUT;     // N*64
    float* e1 = feat2 + N_NODES * OUT_DIM;      // E*4
    float* e2 = e1 + N_EDGES * HEADS;           // E
    float* el1 = e2 + N_EDGES;                  // N*4
    float* er1 = el1 + N_NODES * HEADS;         // N*4
    float* denom1 = er1 + N_NODES * HEADS;      // N*4
    unsigned* emax1 = (unsigned*)(denom1 + N_NODES * HEADS); // N*4
    float* el2 = (float*)(emax1 + N_NODES * HEADS);          // N
    float* er2 = el2 + N_NODES;                 // N
    float* denom2 = er2 + N_NODES;              // N
    unsigned* emax2 = (unsigned*)(denom2 + N_NODES);         // N

    // init accumulators (harness does not re-poison between replays)
    hipMemsetAsync(rst1, 0, (size_t)N_NODES * L1_OUT * sizeof(float), stream);
    hipMemsetAsync(denom1, 0, (size_t)N_NODES * HEADS * sizeof(float), stream);
    hipMemsetAsync(denom2, 0, (size_t)N_NODES * sizeof(float), stream);
    hipMemsetAsync(d_out, 0, (size_t)N_NODES * OUT_DIM * sizeof(float), stream);
    init_emax_kernel<<<(N_NODES * HEADS + 255) / 256, 256, 0, stream>>>(emax1, emax2);

    // layer 1
    gemm1_kernel<<<N_NODES, 256, 0, stream>>>(features, W1, al1, ar1, feat1, el1, er1);
    edge1_logits_kernel<<<(N_EDGES * HEADS + 255) / 256, 256, 0, stream>>>(src, dst, el1, er1, e1, emax1);
    edge1_exp_kernel<<<(N_EDGES * HEADS + 255) / 256, 256, 0, stream>>>(dst, e1, emax1, denom1);
    edge1_scatter_kernel<<<N_EDGES, 256, 0, stream>>>(src, dst, e1, denom1, feat1, rst1);

    // layer 2
    gemm2_kernel<<<N_NODES, 64, 0, stream>>>(rst1, b1, W2, al2, ar2, feat2, el2, er2);
    edge2_logits_kernel<<<(N_EDGES + 255) / 256, 256, 0, stream>>>(src, dst, el2, er2, e2, emax2);
    edge2_exp_kernel<<<(N_EDGES + 255) / 256, 256, 0, stream>>>(dst, e2, emax2, denom2);
    edge2_scatter_kernel<<<N_EDGES, 64, 0, stream>>>(src, dst, e2, denom2, feat2, out);
    bias2_kernel<<<(N_NODES * OUT_DIM + 255) / 256, 256, 0, stream>>>(out, b2);
}

// Round 2
// 365.956 us; speedup vs baseline: 2.3110x; 2.3110x over previous
//
#include <hip/hip_runtime.h>
#include <hip/hip_bf16.h>

#define N_NODES 50000
#define N_EDGES 400000
#define IN_DIM 128
#define HID 64
#define HEADS 4
#define L1_OUT (HEADS * HID)   // 256
#define OUT_DIM 64
#define NEG_SLOPE 0.2f

#define NB1 16   // nodes per block, gemm1
#define NB2 16   // nodes per block, gemm2
#define SCAN_B 256

__device__ __forceinline__ float leaky(float x) { return x > 0.f ? x : NEG_SLOPE * x; }

// ---------------- CSR build ----------------
__global__ void hist_kernel(const int* __restrict__ dst, int* __restrict__ cnt) {
    int e = blockIdx.x * blockDim.x + threadIdx.x;
    if (e < N_EDGES) atomicAdd(&cnt[dst[e]], 1);
}

// per-block exclusive scan of 256-elt tiles; emits tile sums
__global__ void scanA_kernel(const int* __restrict__ cnt, int* __restrict__ texcl,
                             int* __restrict__ bsum) {
    __shared__ int sh[SCAN_B];
    int tid = threadIdx.x;
    int i = blockIdx.x * SCAN_B + tid;
    int v = (i < N_NODES) ? cnt[i] : 0;
    sh[tid] = v;
    __syncthreads();
    for (int off = 1; off < SCAN_B; off <<= 1) {
        int t = (tid >= off) ? sh[tid - off] : 0;
        __syncthreads();
        sh[tid] += t;
        __syncthreads();
    }
    if (i < N_NODES) texcl[i] = sh[tid] - v;   // exclusive within tile
    if (tid == SCAN_B - 1) bsum[blockIdx.x] = sh[tid];
}

// scan the (<=256) tile sums
__global__ void scanB_kernel(const int* __restrict__ bsum, int* __restrict__ bexcl, int nb) {
    __shared__ int sh[SCAN_B];
    int tid = threadIdx.x;
    int v = (tid < nb) ? bsum[tid] : 0;
    sh[tid] = v;
    __syncthreads();
    for (int off = 1; off < SCAN_B; off <<= 1) {
        int t = (tid >= off) ? sh[tid - off] : 0;
        __syncthreads();
        sh[tid] += t;
        __syncthreads();
    }
    if (tid < nb) bexcl[tid] = sh[tid] - v;
}

__global__ void scanC_kernel(const int* __restrict__ texcl, const int* __restrict__ bexcl,
                             int* __restrict__ row) {
    int i = blockIdx.x * blockDim.x + threadIdx.x;
    if (i < N_NODES) row[i] = texcl[i] + bexcl[i >> 8];
    if (blockIdx.x == 0 && threadIdx.x == 0) row[N_NODES] = N_EDGES;
}

__global__ void fill_kernel(const int* __restrict__ src, const int* __restrict__ dst,
                            const int* __restrict__ row, int* __restrict__ fc,
                            int* __restrict__ perm_src) {
    int e = blockIdx.x * blockDim.x + threadIdx.x;
    if (e >= N_EDGES) return;
    int d = dst[e];
    int p = row[d] + atomicAdd(&fc[d], 1);
    perm_src[p] = src[e];
}

// ---------------- layer 1 GEMM: feat1 = X @ W1, 16 nodes/block ----------------
__global__ __launch_bounds__(256) void gemm1_kernel(const float* __restrict__ X,
                                                    const float* __restrict__ W1,
                                                    float* __restrict__ feat1) {
    __shared__ float xs[IN_DIM * 20];   // [k][i], pad 20 keeps 16B alignment
    int n0 = blockIdx.x * NB1;
    int tid = threadIdx.x;
    for (int t = tid; t < NB1 * IN_DIM; t += 256) {
        int i = t >> 7, k = t & (IN_DIM - 1);
        xs[k * 20 + i] = X[(n0 + i) * IN_DIM + k];
    }
    __syncthreads();
    float acc[NB1];
#pragma unroll
    for (int i = 0; i < NB1; ++i) acc[i] = 0.f;
#pragma unroll 4
    for (int k = 0; k < IN_DIM; ++k) {
        float w = W1[k * L1_OUT + tid];
#pragma unroll
        for (int i = 0; i < NB1; ++i) acc[i] += xs[k * 20 + i] * w;
    }
#pragma unroll
    for (int i = 0; i < NB1; ++i) feat1[(n0 + i) * L1_OUT + tid] = acc[i];
}

// ---------------- layer 1 attention coefficients ----------------
__global__ void attn1_kernel(const float* __restrict__ feat1, const float* __restrict__ al,
                             const float* __restrict__ ar, float* __restrict__ el1,
                             float* __restrict__ er1) {
    int n = blockIdx.x;
    int tid = threadIdx.x;      // c = h*64+d
    int h = tid >> 6;
    float f = feat1[n * L1_OUT + tid];
    float l = f * al[tid];
    float r = f * ar[tid];
#pragma unroll
    for (int off = 1; off < 64; off <<= 1) {
        l += __shfl_xor(l, off, 64);
        r += __shfl_xor(r, off, 64);
    }
    if ((tid & 63) == 0) {
        el1[n * HEADS + h] = l;
        er1[n * HEADS + h] = r;
    }
}

// ---------------- layer 1 fused softmax + gather ----------------
__global__ __launch_bounds__(256) void gather1_kernel(const int* __restrict__ row,
                                                      const int* __restrict__ perm_src,
                                                      const float* __restrict__ el1,
                                                      const float* __restrict__ er1,
                                                      const float* __restrict__ feat1,
                                                      float* __restrict__ rst1) {
    int d = blockIdx.x;
    int tid = threadIdx.x;
    int base = row[d];
    int deg = row[d + 1] - base;
    if (deg == 0) { rst1[d * L1_OUT + tid] = 0.f; return; }
    int h = tid >> 6, lane = tid & 63;
    float er_d = er1[d * HEADS + h];

    float m = -1e30f;
    for (int j = lane; j < deg; j += 64) {
        int s = perm_src[base + j];
        m = fmaxf(m, leaky(el1[s * HEADS + h] + er_d));
    }
#pragma unroll
    for (int off = 1; off < 64; off <<= 1) m = fmaxf(m, __shfl_xor(m, off, 64));

    float ssum = 0.f;
    for (int j = lane; j < deg; j += 64) {
        int s = perm_src[base + j];
        ssum += __expf(leaky(el1[s * HEADS + h] + er_d) - m);
    }
#pragma unroll
    for (int off = 1; off < 64; off <<= 1) ssum += __shfl_xor(ssum, off, 64);
    float inv = 1.f / ssum;

    float acc = 0.f;
    for (int j = 0; j < deg; ++j) {
        int s = perm_src[base + j];
        float a = __expf(leaky(el1[s * HEADS + h] + er_d) - m) * inv;
        acc += a * feat1[s * L1_OUT + tid];
    }
    rst1[d * L1_OUT + tid] = acc;
}

// ---------------- layer 2 GEMM: feat2 = (rst1+b1) @ W2, 16 nodes/block ----------------
__global__ __launch_bounds__(256) void gemm2_kernel(const float* __restrict__ rst1,
                                                    const float* __restrict__ b1,
                                                    const float* __restrict__ W2,
                                                    float* __restrict__ feat2) {
    __shared__ float rs[L1_OUT * 20];   // [k][i]
    int n0 = blockIdx.x * NB2;
    int tid = threadIdx.x;
    for (int t = tid; t < NB2 * L1_OUT; t += 256) {
        int i = t >> 8, k = t & (L1_OUT - 1);
        rs[k * 20 + i] = rst1[(n0 + i) * L1_OUT + k] + b1[k];
    }
    __syncthreads();
    int c = tid & 63, g = tid >> 6;     // wave g handles nodes g*4..g*4+3
    float acc[4] = {0.f, 0.f, 0.f, 0.f};
#pragma unroll 4
    for (int k = 0; k < L1_OUT; ++k) {
        float w = W2[k * OUT_DIM + c];
#pragma unroll
        for (int u = 0; u < 4; ++u) acc[u] += rs[k * 20 + g * 4 + u] * w;
    }
#pragma unroll
    for (int u = 0; u < 4; ++u) feat2[(n0 + g * 4 + u) * OUT_DIM + c] = acc[u];
}

// ---------------- layer 2 attention coefficients (4 nodes/block) ----------------
__global__ void attn2_kernel(const float* __restrict__ feat2, const float* __restrict__ al2,
                             const float* __restrict__ ar2, float* __restrict__ el2,
                             float* __restrict__ er2) {
    int tid = threadIdx.x;
    int n = blockIdx.x * 4 + (tid >> 6);
    int dch = tid & 63;
    float f = feat2[n * OUT_DIM + dch];
    float l = f * al2[dch];
    float r = f * ar2[dch];
#pragma unroll
    for (int off = 1; off < 64; off <<= 1) {
        l += __shfl_xor(l, off, 64);
        r += __shfl_xor(r, off, 64);
    }
    if (dch == 0) {
        el2[n] = l;
        er2[n] = r;
    }
}

// ---------------- layer 2 fused softmax + gather (+bias) ----------------
__global__ __launch_bounds__(64) void gather2_kernel(const int* __restrict__ row,
                                                     const int* __restrict__ perm_src,
                                                     const float* __restrict__ el2,
                                                     const float* __restrict__ er2,
                                                     const float* __restrict__ feat2,
                                                     const float* __restrict__ b2,
                                                     float* __restrict__ out) {
    int d = blockIdx.x;
    int c = threadIdx.x;
    int base = row[d];
    int deg = row[d + 1] - base;
    if (deg == 0) { out[d * OUT_DIM + c] = b2[c]; return; }
    float er_d = er2[d];

    float m = -1e30f;
    for (int j = c; j < deg; j += 64) {
        int s = perm_src[base + j];
        m = fmaxf(m, leaky(el2[s] + er_d));
    }
#pragma unroll
    for (int off = 1; off < 64; off <<= 1) m = fmaxf(m, __shfl_xor(m, off, 64));

    float ssum = 0.f;
    for (int j = c; j < deg; j += 64) {
        int s = perm_src[base + j];
        ssum += __expf(leaky(el2[s] + er_d) - m);
    }
#pragma unroll
    for (int off = 1; off < 64; off <<= 1) ssum += __shfl_xor(ssum, off, 64);
    float inv = 1.f / ssum;

    float acc = 0.f;
    for (int j = 0; j < deg; ++j) {
        int s = perm_src[base + j];
        float a = __expf(leaky(el2[s] + er_d) - m) * inv;
        acc += a * feat2[s * OUT_DIM + c];
    }
    out[d * OUT_DIM + c] = acc + b2[c];
}

extern "C" void kernel_launch(void* const* d_in, const int* in_sizes, int n_in,
                              void* d_out, int out_size, void* d_ws, size_t ws_size,
                              hipStream_t stream) {
    const float* features = (const float*)d_in[0];
    const int* src = (const int*)d_in[1];
    const int* dst = (const int*)d_in[2];
    const float* W1 = (const float*)d_in[3];
    const float* al1 = (const float*)d_in[4];
    const float* ar1 = (const float*)d_in[5];
    const float* b1 = (const float*)d_in[6];
    const float* W2 = (const float*)d_in[7];
    const float* al2 = (const float*)d_in[8];
    const float* ar2 = (const float*)d_in[9];
    const float* b2 = (const float*)d_in[10];
    float* out = (float*)d_out;

    // workspace layout
    float* ws = (float*)d_ws;
    float* feat1 = ws;                           // N*256
    float* rst1 = feat1 + (size_t)N_NODES * L1_OUT;  // N*256
    float* feat2 = rst1 + (size_t)N_NODES * L1_OUT;  // N*64
    float* el1 = feat2 + (size_t)N_NODES * OUT_DIM;  // N*4
    float* er1 = el1 + N_NODES * HEADS;          // N*4
    float* el2 = er1 + N_NODES * HEADS;          // N
    float* er2 = el2 + N_NODES;                  // N
    int* cnt = (int*)(er2 + N_NODES);            // N
    int* fc = cnt + N_NODES;                     // N
    int* texcl = fc + N_NODES;                   // N
    int* bsum = texcl + N_NODES;                 // 256
    int* bexcl = bsum + 256;                     // 256
    int* row = bexcl + 256;                      // N+1
    int* perm_src = row + N_NODES + 1;           // E

    const int nb1 = (N_NODES + SCAN_B - 1) / SCAN_B;   // 196

    hipMemsetAsync(cnt, 0, (size_t)N_NODES * sizeof(int), stream);
    hipMemsetAsync(fc, 0, (size_t)N_NODES * sizeof(int), stream);

    // CSR build
    hist_kernel<<<(N_EDGES + 255) / 256, 256, 0, stream>>>(dst, cnt);
    scanA_kernel<<<nb1, SCAN_B, 0, stream>>>(cnt, texcl, bsum);
    scanB_kernel<<<1, SCAN_B, 0, stream>>>(bsum, bexcl, nb1);
    scanC_kernel<<<(N_NODES + 255) / 256, 256, 0, stream>>>(texcl, bexcl, row);
    fill_kernel<<<(N_EDGES + 255) / 256, 256, 0, stream>>>(src, dst, row, fc, perm_src);

    // layer 1
    gemm1_kernel<<<N_NODES / NB1, 256, 0, stream>>>(features, W1, feat1);
    attn1_kernel<<<N_NODES, 256, 0, stream>>>(feat1, al1, ar1, el1, er1);
    gather1_kernel<<<N_NODES, 256, 0, stream>>>(row, perm_src, el1, er1, feat1, rst1);

    // layer 2
    gemm2_kernel<<<N_NODES / NB2, 256, 0, stream>>>(rst1, b1, W2, feat2);
    attn2_kernel<<<N_NODES / 4, 256, 0, stream>>>(feat2, al2, ar2, el2, er2);
    gather2_kernel<<<N_NODES, 64, 0, stream>>>(row, perm_src, el2, er2, feat2, b2, out);
}